// Round 6
// baseline (1570.256 us; speedup 1.0000x reference)
//
#include <hip/hip_runtime.h>
#include <math.h>

#define D 256
#define TOPK 1024
#define EPS 1e-8f

__device__ __forceinline__ unsigned encf(float f){
  unsigned b = __float_as_uint(f);
  return b ^ ((unsigned)((int)b >> 31) | 0x80000000u);
}
__device__ __forceinline__ float decf(unsigned u){
  unsigned b = (u & 0x80000000u) ? (u ^ 0x80000000u) : ~u;
  return __uint_as_float(b);
}

// Upper-triangle tiles (a<=b) in storage order t=0..35; packed a*8+b.
static __device__ const unsigned char TL36[36] = {
  0,1,2,3,4,5,6,7,
  9,10,11,12,13,14,15,
  18,19,20,21,22,23,
  27,28,29,30,31,
  36,37,38,39,
  45,46,47,
  54,55,
  63
};

// ---------------------------------------------------------------------------
// K1: precompute UT = TILED sym-folded W_e^T W_e (36 contiguous 4KB tiles in
// TL36 order), r_e, B[3][256], C[3], rc[3], |q|; zero H0 + scalars.
// ---------------------------------------------------------------------------
__global__ __launch_bounds__(256) void k1_setup(
    const float* __restrict__ emb, const float* __restrict__ dtab,
    const float* __restrict__ W, const int* __restrict__ srcp,
    float* __restrict__ UT, float* __restrict__ RE, float* __restrict__ Bm,
    float* __restrict__ Cc, float* __restrict__ RC, float* __restrict__ QN,
    unsigned* __restrict__ SC, unsigned* __restrict__ H0)
{
  int tid = threadIdx.x;
  int gid = blockIdx.x*256 + tid;
  if (gid < 2048) H0[gid] = 0u;
  if (gid == 0){
    SC[0]=0u;                 // MAXE (encoded max logit)
    ((float*)SC)[1]=0.0f;     // SUME
    SC[2]=0u;                 // EQC
    SC[3]=0u;                 // T (threshold key, set by ksel)
    SC[4]=(unsigned)TOPK;     // KP (quota at ==T, set by ksel)
    SC[5]=0u;                 // DONE counter for k6
    SC[6]=0u; SC[7]=0u;
  }
  __shared__ float red[256];
  __shared__ float r67[2];
  if (blockIdx.x < 256){
    int kr = blockIdx.x;      // row of A
    int kc = tid;             // col (coalesced)
    float acc=0.f;
    for (int j=0;j<D;++j)
      acc = fmaf(W[(size_t)j*258 + kr], W[(size_t)j*258 + kc], acc);
    float uv = (kr==kc) ? acc : (kr<kc ? 2.0f*acc : 0.0f);
    int a = kr>>5, b2 = kc>>5;
    if (b2 >= a){
      int tidx = a*8 - (a*(a-1))/2 + (b2-a);   // index in TL36 order
      UT[(size_t)tidx*1024 + (kr&31)*32 + (kc&31)] = uv;
    }
  } else {
    int src = srcp[0];
    const float* qv = emb + (size_t)src*D;
    float dt00=dtab[0],dt01=dtab[1],dt10=dtab[2],dt11=dtab[3],dt20=dtab[4],dt21=dtab[5];
    int k = tid;
    float r=0.f,b0=0.f,b1=0.f,b2=0.f;
    for (int j=0;j<D;++j){
      float wk = W[(size_t)j*258 + k];
      float qj = qv[j];
      float w6 = W[(size_t)j*258 + 256];
      float w7 = W[(size_t)j*258 + 257];
      r  = fmaf(qj, wk, r);
      b0 = fmaf(fmaf(w6,dt00, w7*dt01), wk, b0);
      b1 = fmaf(fmaf(w6,dt10, w7*dt11), wk, b1);
      b2 = fmaf(fmaf(w6,dt20, w7*dt21), wk, b2);
    }
    RE[k]=r; Bm[k]=2.f*b0; Bm[256+k]=2.f*b1; Bm[512+k]=2.f*b2;
    float qk = qv[k];
    red[tid]=qk*qk; __syncthreads();
    for (int s2=128;s2>0;s2>>=1){ if (tid<s2) red[tid]+=red[tid+s2]; __syncthreads(); }
    if (tid==0) QN[0] = sqrtf(red[0]);
    if (tid==3 || tid==4){
      int col = 256 + (tid-3);
      float a2=0.f;
      for (int j=0;j<D;++j) a2 = fmaf(qv[j], W[(size_t)j*258+col], a2);
      r67[tid-3]=a2;
    }
    if (tid<3){
      float d0=dtab[2*tid], d1=dtab[2*tid+1];
      float a2=0.f;
      for (int j=0;j<D;++j){
        float v = fmaf(W[(size_t)j*258+256],d0, W[(size_t)j*258+257]*d1);
        a2 = fmaf(v,v,a2);
      }
      Cc[tid]=a2;
    }
    __syncthreads();
    if (tid<3){
      float d0=dtab[2*tid], d1=dtab[2*tid+1];
      RC[tid] = r67[0]*d0 + r67[1]*d1;
    }
  }
}

// ---------------------------------------------------------------------------
// K2: Q = x^T U x. Block = 4 waves, 64 rows (lane = row). ALL waves walk the
// SAME 36-tile sequence (shared scalar working set); wave w handles tile
// columns [8w,8w+8): partial row-sums over its 8 cols, outer-FMA with xa.
// Tiles contiguous (4KB) -> s_load_dwordx8 rows; 2-row ping-pong pipelines
// scalar latency. Wave 0 also does r-dot/B-dot + epilogue + fused histogram.
// ---------------------------------------------------------------------------
#define LOADC(dst, c) do { const float4* _p=(const float4*)(xrow+(c)*32); \
  _Pragma("unroll") for(int _i=0;_i<8;++_i){ float4 _v=_p[_i]; \
  dst[4*_i]=_v.x; dst[4*_i+1]=_v.y; dst[4*_i+2]=_v.z; dst[4*_i+3]=_v.w; } } while(0)

#define LD8(dst, rr) do { const float4* _p=(const float4*)(Ur+(size_t)(rr)*32); \
  float4 _a=_p[0], _b=_p[1]; \
  dst[0]=_a.x; dst[1]=_a.y; dst[2]=_a.z; dst[3]=_a.w; \
  dst[4]=_b.x; dst[5]=_b.y; dst[6]=_b.z; dst[7]=_b.w; } while(0)

#define DOT8(C, XAV) do { float _t0,_t1,_t2,_t3; \
  _t0=C[0]*xbw[0]; _t1=C[1]*xbw[1]; _t2=C[2]*xbw[2]; _t3=C[3]*xbw[3]; \
  _t0=fmaf(C[4],xbw[4],_t0); _t1=fmaf(C[5],xbw[5],_t1); \
  _t2=fmaf(C[6],xbw[6],_t2); _t3=fmaf(C[7],xbw[7],_t3); \
  qacc = fmaf(XAV, (_t0+_t1)+(_t2+_t3), qacc); } while(0)

__global__ __launch_bounds__(256) void k2_main(
    const float* __restrict__ emb, const int* __restrict__ dist,
    const float* __restrict__ UT, const float* __restrict__ RE,
    const float* __restrict__ Bm, const float* __restrict__ Cc,
    const float* __restrict__ RC, const float* __restrict__ QN,
    float* __restrict__ Sv, unsigned* __restrict__ UK,
    unsigned* __restrict__ SC, unsigned* __restrict__ H0, int N)
{
  int tid = threadIdx.x;
  int wave = tid >> 6;
  int lane = tid & 63;
  int row = blockIdx.x*64 + lane;
  bool ok = row < N;
  const float* xrow = emb + (size_t)(ok?row:0)*D;
  int dv = 3, didx = 2;
  float xa[32], xbw[8];
  float qacc=0.f, sacc=0.f;

  __shared__ float qred[256];
  __shared__ unsigned h[2048];
  for (int i=tid;i<2048;i+=256) h[i]=0u;

  if (wave==0){
    dv = ok ? dist[row] : 3;
    didx = dv-1; didx = didx<0?0:(didx>2?2:didx);
    const float* Bv = Bm + didx*256;
    for (int c=0;c<8;++c){
      LOADC(xa,c);
      #pragma unroll
      for (int i=0;i<32;++i){
        sacc = fmaf(xa[i], RE[c*32+i], sacc);   // uniform -> s_load
        qacc = fmaf(xa[i], Bv[c*32+i], qacc);   // per-lane, cache-hot
      }
    }
  }

  int aprev = -1;
  for (int t=0;t<36;++t){
    int ab = __builtin_amdgcn_readfirstlane((int)TL36[t]);
    int a = ab>>3, b = ab&7;
    if (a != aprev){ LOADC(xa,a); aprev = a; }
    {
      const float4* p = (const float4*)(xrow + b*32 + wave*8);
      float4 v0=p[0], v1=p[1];
      xbw[0]=v0.x; xbw[1]=v0.y; xbw[2]=v0.z; xbw[3]=v0.w;
      xbw[4]=v1.x; xbw[5]=v1.y; xbw[6]=v1.z; xbw[7]=v1.w;
    }
    const float* Ur = UT + (size_t)t*1024 + wave*8;   // this wave's 8 cols
    float c0[8], c1[8];
    LD8(c0,0);
    #pragma unroll
    for (int r=0;r<32;r+=2){
      LD8(c1,r+1);
      DOT8(c0, xa[r]);
      if (r+2<32) LD8(c0,r+2);
      DOT8(c1, xa[r+1]);
    }
  }

  qred[tid] = qacc;
  __syncthreads();

  if (wave==0){
    float qtot = qacc + qred[64+lane] + qred[128+lane] + qred[192+lane];
    float Q = qtot + Cc[didx];
    float s = sacc + RC[didx];
    float qn = QN[0];
    float denom = fmaxf(sqrtf(Q), EPS) * fmaxf(qn, EPS);
    float cosv = s/denom;
    float wgt = (dv==1)?1.5f : ((dv==2)?2.0f:1.0f);
    float wv = (dv<=2) ? cosv*wgt : -INFINITY;
    unsigned u = encf(wv);
    if (ok){ Sv[row]=s; UK[row]=u; if (u > 0x007FFFFFu) atomicAdd(&h[u>>21],1u); }
    float m = ok ? s : -INFINITY;
    #pragma unroll
    for (int off=32;off>0;off>>=1) m = fmaxf(m, __shfl_down(m, off));
    if (lane==0) atomicMax(&SC[0], encf(m));
  }
  __syncthreads();
  for (int i=tid;i<2048;i+=256){ unsigned v=h[i]; if (v) atomicAdd(&H0[i], v); }
}

// ---------------------------------------------------------------------------
// KSEL: single-block 3-pass radix select (bits 31:21 from H0, then 20:10,
// then 9:0 re-scanning UK). Writes T -> SC[3], quota-at-T -> SC[4].
// ---------------------------------------------------------------------------
__global__ __launch_bounds__(1024) void ksel(
    const unsigned* __restrict__ UK, unsigned* __restrict__ SC,
    const unsigned* __restrict__ H0, int N)
{
  __shared__ unsigned h[2048];
  __shared__ unsigned part[1024];
  __shared__ unsigned sPfx, sKp;
  int tid = threadIdx.x;

  unsigned v0 = H0[2*tid], v1 = H0[2*tid+1];
  h[2*tid]=v0; h[2*tid+1]=v1; part[tid]=v0+v1;
  __syncthreads();
  if (tid==0){
    unsigned Kp = TOPK, cum=0; int st=0;
    for (int t=1023;t>=0;--t){ if (cum+part[t]>=Kp){st=t;break;} cum+=part[t]; }
    int sel = 2*st;
    for (int b=2*st+1;b>=2*st;--b){ if (cum+h[b]>=Kp){sel=b;break;} cum+=h[b]; }
    sPfx = (unsigned)sel; sKp = Kp - cum;
  }
  __syncthreads();
  unsigned pfx = sPfx;
  __syncthreads();

  h[2*tid]=0u; h[2*tid+1]=0u;
  __syncthreads();
  for (int i=tid;i<N;i+=1024){
    unsigned u = UK[i];
    if ((u>>21)==pfx) atomicAdd(&h[(u>>10)&2047u],1u);
  }
  __syncthreads();
  part[tid]=h[2*tid]+h[2*tid+1];
  __syncthreads();
  if (tid==0){
    unsigned Kp = sKp, cum=0; int st=0;
    for (int t=1023;t>=0;--t){ if (cum+part[t]>=Kp){st=t;break;} cum+=part[t]; }
    int sel = 2*st;
    for (int b=2*st+1;b>=2*st;--b){ if (cum+h[b]>=Kp){sel=b;break;} cum+=h[b]; }
    sPfx = (pfx<<11)|(unsigned)sel; sKp = Kp - cum;
  }
  __syncthreads();
  pfx = sPfx;
  __syncthreads();

  h[tid]=0u;
  __syncthreads();
  for (int i=tid;i<N;i+=1024){
    unsigned u = UK[i];
    if ((u>>10)==pfx) atomicAdd(&h[u&1023u],1u);
  }
  __syncthreads();
  if (tid==0){
    unsigned Kp = sKp, cum=0; int sel=0;
    for (int t=1023;t>=0;--t){ if (cum+h[t]>=Kp){sel=t;break;} cum+=h[t]; }
    SC[3] = (pfx<<10)|(unsigned)sel;
    SC[4] = Kp - cum;
  }
}

// ---------------------------------------------------------------------------
// K6: mask write (topk-strict | dist==1 | src), ==T collect, sum-exp; LAST
// block (device-scope done-counter) fuses loss + tie resolution.
// ---------------------------------------------------------------------------
__global__ __launch_bounds__(256) void k6_final(
    const int* __restrict__ dist, const int* __restrict__ srcp,
    const int* __restrict__ labels,
    const float* __restrict__ Sv, const unsigned* __restrict__ UK,
    unsigned* SC, unsigned* EQL,
    float* __restrict__ out, int N, int L)
{
  int tid=threadIdx.x;
  int n=blockIdx.x*256+tid;
  unsigned T = SC[3];
  float M = decf(SC[0]);
  int src = srcp[0];
  float e=0.f;
  if (n<N){
    unsigned u = UK[n];
    int dv = dist[n];
    bool base = (u>T) || (dv==1) || (n==src);
    out[1+n] = base ? 1.0f : 0.0f;
    if (u==T){
      unsigned i = atomicAdd(&SC[2], 1u);
      if (i < 4096u)
        __hip_atomic_store(&EQL[i], (unsigned)n, __ATOMIC_RELAXED, __HIP_MEMORY_SCOPE_AGENT);
    }
    e = expf(Sv[n]-M);
  }
  __shared__ float red[256];
  __shared__ int lastflag;
  __shared__ unsigned lst[4096];
  red[tid]=e; __syncthreads();
  for (int st=128;st>0;st>>=1){ if (tid<st) red[tid]+=red[tid+st]; __syncthreads(); }
  if (tid==0) atomicAdd((float*)&SC[1], red[0]);
  __threadfence();
  __syncthreads();
  if (tid==0){
    unsigned d = atomicAdd(&SC[5], 1u);
    lastflag = (d == gridDim.x-1) ? 1 : 0;
  }
  __syncthreads();
  if (!lastflag) return;
  __threadfence();

  float v = 0.f;
  if (tid<L) v = Sv[labels[tid]];
  red[tid]=v; __syncthreads();
  for (int st=128;st>0;st>>=1){ if (tid<st) red[tid]+=red[tid+st]; __syncthreads(); }
  if (tid==0){
    float se = __hip_atomic_load((float*)&SC[1], __ATOMIC_RELAXED, __HIP_MEMORY_SCOPE_AGENT);
    out[0] = (float)L*(M + logf(se)) - red[0];
  }
  unsigned cnt = __hip_atomic_load(&SC[2], __ATOMIC_RELAXED, __HIP_MEMORY_SCOPE_AGENT);
  if (cnt>4096u) cnt=4096u;
  unsigned quota = SC[4];
  for (unsigned i=tid;i<cnt;i+=256u)
    lst[i] = __hip_atomic_load(&EQL[i], __ATOMIC_RELAXED, __HIP_MEMORY_SCOPE_AGENT);
  __syncthreads();
  if (cnt <= quota){
    for (unsigned i=tid;i<cnt;i+=256u) out[1+lst[i]] = 1.0f;
  } else {
    for (unsigned i=tid;i<cnt;i+=256u){
      unsigned me=lst[i], rank=0;
      for (unsigned j=0;j<cnt;++j) rank += (lst[j]<me)?1u:0u;
      if (rank<quota) out[1+me]=1.0f;   // stable tie-break: lowest index wins
    }
  }
}

extern "C" void kernel_launch(void* const* d_in, const int* in_sizes, int n_in,
                              void* d_out, int out_size, void* d_ws, size_t ws_size,
                              hipStream_t stream)
{
  const float* emb  = (const float*)d_in[0];
  const float* dtab = (const float*)d_in[1];
  const float* W    = (const float*)d_in[2];
  const int* dist   = (const int*)d_in[3];
  const int* labels = (const int*)d_in[4];
  const int* srcp   = (const int*)d_in[5];
  float* out = (float*)d_out;
  int N = in_sizes[3];
  int L = in_sizes[4];

  float* ws = (float*)d_ws;
  float* UT = ws;                       // 36*1024 = 36864
  float* RE = UT + 36864;               // 256
  float* Bm = RE + 256;                 // 768
  float* Cc = Bm + 768;                 // 3
  float* RC = Cc + 3;                   // 3
  float* QN = RC + 3;                   // 1
  unsigned* SC = (unsigned*)(QN + 1);   // 8 scalars
  unsigned* H0 = SC + 8;                // 2048
  float* Sv = (float*)(H0 + 2048);      // N
  unsigned* UK = (unsigned*)(Sv + N);   // N
  unsigned* EQL = UK + N;               // 4096

  int grid  = (N + 255)/256;
  int grid2 = (N + 63)/64;
  k1_setup<<<257,256,0,stream>>>(emb, dtab, W, srcp, UT, RE, Bm, Cc, RC, QN, SC, H0);
  k2_main<<<grid2,256,0,stream>>>(emb, dist, UT, RE, Bm, Cc, RC, QN, Sv, UK, SC, H0, N);
  ksel<<<1,1024,0,stream>>>(UK, SC, H0, N);
  k6_final<<<grid,256,0,stream>>>(dist, srcp, labels, Sv, UK, SC, EQL, out, N, L);
}

// Round 7
// 987.040 us; speedup vs baseline: 1.5909x; 1.5909x over previous
//
#include <hip/hip_runtime.h>
#include <math.h>

#define D 256
#define TOPK 1024
#define EPS 1e-8f
#define EQCAP 32768u

__device__ __forceinline__ unsigned encf(float f){
  unsigned b = __float_as_uint(f);
  return b ^ ((unsigned)((int)b >> 31) | 0x80000000u);
}
__device__ __forceinline__ float decf(unsigned u){
  unsigned b = (u & 0x80000000u) ? (u ^ 0x80000000u) : ~u;
  return __uint_as_float(b);
}

// Upper-triangle tiles (a<=b) in storage order t=0..35; packed a*8+b.
static __device__ const unsigned char TL36[36] = {
  0,1,2,3,4,5,6,7,
  9,10,11,12,13,14,15,
  18,19,20,21,22,23,
  27,28,29,30,31,
  36,37,38,39,
  45,46,47,
  54,55,
  63
};

// ---------------------------------------------------------------------------
// K1: precompute UT = TILED sym-folded W_e^T W_e (36 contiguous 4KB tiles in
// TL36 order), r_e, B[3][256], C[3], rc[3], |q|; zero H0 + scalars.
// ---------------------------------------------------------------------------
__global__ __launch_bounds__(256) void k1_setup(
    const float* __restrict__ emb, const float* __restrict__ dtab,
    const float* __restrict__ W, const int* __restrict__ srcp,
    float* __restrict__ UT, float* __restrict__ RE, float* __restrict__ Bm,
    float* __restrict__ Cc, float* __restrict__ RC, float* __restrict__ QN,
    unsigned* __restrict__ SC, unsigned* __restrict__ H0)
{
  int tid = threadIdx.x;
  int gid = blockIdx.x*256 + tid;
  if (gid < 2048) H0[gid] = 0u;
  if (gid == 0){
    SC[0]=0u;                 // MAXE (encoded max logit)
    ((float*)SC)[1]=0.0f;     // SUME
    SC[2]=0u;                 // EQC (candidate count)
    SC[3]=0u;                 // (unused)
    SC[4]=(unsigned)TOPK;     // quota within boundary bin (set by ksel0)
    SC[5]=0u;                 // DONE counter for k6
    SC[6]=0u;                 // boundary bin (set by ksel0)
    SC[7]=0u;
  }
  __shared__ float red[256];
  __shared__ float r67[2];
  if (blockIdx.x < 256){
    int kr = blockIdx.x;      // row of A
    int kc = tid;             // col (coalesced)
    float acc=0.f;
    for (int j=0;j<D;++j)
      acc = fmaf(W[(size_t)j*258 + kr], W[(size_t)j*258 + kc], acc);
    float uv = (kr==kc) ? acc : (kr<kc ? 2.0f*acc : 0.0f);
    int a = kr>>5, b2 = kc>>5;
    if (b2 >= a){
      int tidx = a*8 - (a*(a-1))/2 + (b2-a);   // index in TL36 order
      UT[(size_t)tidx*1024 + (kr&31)*32 + (kc&31)] = uv;
    }
  } else {
    int src = srcp[0];
    const float* qv = emb + (size_t)src*D;
    float dt00=dtab[0],dt01=dtab[1],dt10=dtab[2],dt11=dtab[3],dt20=dtab[4],dt21=dtab[5];
    int k = tid;
    float r=0.f,b0=0.f,b1=0.f,b2=0.f;
    for (int j=0;j<D;++j){
      float wk = W[(size_t)j*258 + k];
      float qj = qv[j];
      float w6 = W[(size_t)j*258 + 256];
      float w7 = W[(size_t)j*258 + 257];
      r  = fmaf(qj, wk, r);
      b0 = fmaf(fmaf(w6,dt00, w7*dt01), wk, b0);
      b1 = fmaf(fmaf(w6,dt10, w7*dt11), wk, b1);
      b2 = fmaf(fmaf(w6,dt20, w7*dt21), wk, b2);
    }
    RE[k]=r; Bm[k]=2.f*b0; Bm[256+k]=2.f*b1; Bm[512+k]=2.f*b2;
    float qk = qv[k];
    red[tid]=qk*qk; __syncthreads();
    for (int s2=128;s2>0;s2>>=1){ if (tid<s2) red[tid]+=red[tid+s2]; __syncthreads(); }
    if (tid==0) QN[0] = sqrtf(red[0]);
    if (tid==3 || tid==4){
      int col = 256 + (tid-3);
      float a2=0.f;
      for (int j=0;j<D;++j) a2 = fmaf(qv[j], W[(size_t)j*258+col], a2);
      r67[tid-3]=a2;
    }
    if (tid<3){
      float d0=dtab[2*tid], d1=dtab[2*tid+1];
      float a2=0.f;
      for (int j=0;j<D;++j){
        float v = fmaf(W[(size_t)j*258+256],d0, W[(size_t)j*258+257]*d1);
        a2 = fmaf(v,v,a2);
      }
      Cc[tid]=a2;
    }
    __syncthreads();
    if (tid<3){
      float d0=dtab[2*tid], d1=dtab[2*tid+1];
      RC[tid] = r67[0]*d0 + r67[1]*d1;
    }
  }
}

// ---------------------------------------------------------------------------
// K2: Q = x^T U x. Block = 4 waves, 64 rows (lane = row). ALL waves walk the
// SAME 36-tile sequence (shared ~4KB scalar working set -> sL1-hot); wave w
// handles tile columns [8w,8w+8). CRITICAL: wave id passes through
// readfirstlane so the U addresses are provably uniform -> s_load (R6 used
// raw tid>>6 and the loads became per-lane vector loads: 2.5x regression).
// 2-row ping-pong (SGPR) pipelines scalar-load latency.
// ---------------------------------------------------------------------------
#define LOADC(dst, c) do { const float4* _p=(const float4*)(xrow+(c)*32); \
  _Pragma("unroll") for(int _i=0;_i<8;++_i){ float4 _v=_p[_i]; \
  dst[4*_i]=_v.x; dst[4*_i+1]=_v.y; dst[4*_i+2]=_v.z; dst[4*_i+3]=_v.w; } } while(0)

#define LD8(dst, rr) do { _Pragma("unroll") for(int _j=0;_j<8;++_j) \
  dst[_j] = Ur[(rr)*32 + _j]; } while(0)

#define DOT8(C, XAV) do { float _t0,_t1,_t2,_t3; \
  _t0=C[0]*xbw[0]; _t1=C[1]*xbw[1]; _t2=C[2]*xbw[2]; _t3=C[3]*xbw[3]; \
  _t0=fmaf(C[4],xbw[4],_t0); _t1=fmaf(C[5],xbw[5],_t1); \
  _t2=fmaf(C[6],xbw[6],_t2); _t3=fmaf(C[7],xbw[7],_t3); \
  qacc = fmaf(XAV, (_t0+_t1)+(_t2+_t3), qacc); } while(0)

__global__ __launch_bounds__(256) void k2_main(
    const float* __restrict__ emb, const int* __restrict__ dist,
    const float* __restrict__ UT, const float* __restrict__ RE,
    const float* __restrict__ Bm, const float* __restrict__ Cc,
    const float* __restrict__ RC, const float* __restrict__ QN,
    float* __restrict__ Sv, unsigned* __restrict__ UK,
    unsigned* __restrict__ SC, unsigned* __restrict__ H0, int N)
{
  int tid = threadIdx.x;
  int wave = __builtin_amdgcn_readfirstlane(tid >> 6);   // SGPR-provable
  int lane = tid & 63;
  int row = blockIdx.x*64 + lane;
  bool ok = row < N;
  const float* xrow = emb + (size_t)(ok?row:0)*D;
  int dv = 3, didx = 2;
  float xa[32], xbw[8];
  float qacc=0.f, sacc=0.f;

  __shared__ float qred[256];
  __shared__ unsigned h[2048];
  for (int i=tid;i<2048;i+=256) h[i]=0u;

  if (wave==0){
    dv = ok ? dist[row] : 3;
    didx = dv-1; didx = didx<0?0:(didx>2?2:didx);
    const float* Bv = Bm + didx*256;
    for (int c=0;c<8;++c){
      LOADC(xa,c);
      #pragma unroll
      for (int i=0;i<32;++i){
        sacc = fmaf(xa[i], RE[c*32+i], sacc);   // uniform -> s_load
        qacc = fmaf(xa[i], Bv[c*32+i], qacc);   // per-lane, cache-hot
      }
    }
  }

  int aprev = -1;
  for (int t=0;t<36;++t){
    int ab = __builtin_amdgcn_readfirstlane((int)TL36[t]);
    int a = ab>>3, b = ab&7;
    if (a != aprev){ LOADC(xa,a); aprev = a; }
    {
      const float4* p = (const float4*)(xrow + b*32 + wave*8);
      float4 v0=p[0], v1=p[1];
      xbw[0]=v0.x; xbw[1]=v0.y; xbw[2]=v0.z; xbw[3]=v0.w;
      xbw[4]=v1.x; xbw[5]=v1.y; xbw[6]=v1.z; xbw[7]=v1.w;
    }
    const float* Ur = UT + (size_t)t*1024 + wave*8;   // uniform base
    float c0[8], c1[8];
    LD8(c0,0);
    #pragma unroll
    for (int r=0;r<32;r+=2){
      LD8(c1,r+1);
      DOT8(c0, xa[r]);
      if (r+2<32) LD8(c0,r+2);
      DOT8(c1, xa[r+1]);
    }
  }

  qred[tid] = qacc;
  __syncthreads();

  if (wave==0){
    float qtot = qacc + qred[64+lane] + qred[128+lane] + qred[192+lane];
    float Q = qtot + Cc[didx];
    float s = sacc + RC[didx];
    float qn = QN[0];
    float denom = fmaxf(sqrtf(Q), EPS) * fmaxf(qn, EPS);
    float cosv = s/denom;
    float wgt = (dv==1)?1.5f : ((dv==2)?2.0f:1.0f);
    float wv = (dv<=2) ? cosv*wgt : -INFINITY;
    unsigned u = encf(wv);
    if (ok){ Sv[row]=s; UK[row]=u; if (u > 0x007FFFFFu) atomicAdd(&h[u>>21],1u); }
    float m = ok ? s : -INFINITY;
    #pragma unroll
    for (int off=32;off>0;off>>=1) m = fmaxf(m, __shfl_down(m, off));
    if (lane==0) atomicMax(&SC[0], encf(m));
  }
  __syncthreads();
  for (int i=tid;i<2048;i+=256){ unsigned v=h[i]; if (v) atomicAdd(&H0[i], v); }
}

// ---------------------------------------------------------------------------
// KSEL0: tiny single-block scan of the 2048-bin histogram. Picks the boundary
// 11-bit bin (SC[6]) and the quota within it (SC[4]). No N-scans.
// ---------------------------------------------------------------------------
__global__ __launch_bounds__(256) void ksel0(
    unsigned* __restrict__ SC, const unsigned* __restrict__ H0)
{
  __shared__ unsigned h[2048];
  __shared__ unsigned part[256];
  int tid = threadIdx.x;
  unsigned ps=0;
  for (int i=0;i<8;++i){ unsigned v=H0[tid*8+i]; h[tid*8+i]=v; ps+=v; }
  part[tid]=ps;
  __syncthreads();
  if (tid==0){
    unsigned K=TOPK, cum=0; int st=0;
    for (int t=255;t>=0;--t){ if (cum+part[t]>=K){st=t;break;} cum+=part[t]; }
    int sel = st*8;
    for (int b=st*8+7;b>=st*8;--b){ if (cum+h[b]>=K){sel=b;break;} cum+=h[b]; }
    SC[6] = (unsigned)sel;     // boundary bin
    SC[4] = K - cum;           // quota within boundary bin (>=1)
  }
}

// ---------------------------------------------------------------------------
// K6: mask write (bin>selbin | dist==1 | src), collect bin==selbin candidates,
// sum-exp. LAST block (device-scope done-counter): exact radix-select of the
// threshold among the candidates (3x7-bit LDS passes over the candidate list
// only), candidate marking with lowest-index-first ties, and the loss.
// ---------------------------------------------------------------------------
__global__ __launch_bounds__(256) void k6_final(
    const int* __restrict__ dist, const int* __restrict__ srcp,
    const int* __restrict__ labels,
    const float* __restrict__ Sv, const unsigned* __restrict__ UK,
    unsigned* SC, unsigned* EQL,
    float* __restrict__ out, int N, int L)
{
  int tid=threadIdx.x;
  int n=blockIdx.x*256+tid;
  unsigned selbin = SC[6];
  float M = decf(SC[0]);
  int src = srcp[0];
  float e=0.f;
  if (n<N){
    unsigned u = UK[n];
    int dv = dist[n];
    unsigned bin = u>>21;
    bool base = (bin>selbin) || (dv==1) || (n==src);
    out[1+n] = base ? 1.0f : 0.0f;
    if (bin==selbin){
      unsigned i = atomicAdd(&SC[2], 1u);
      if (i < EQCAP)
        __hip_atomic_store(&EQL[i], (unsigned)n, __ATOMIC_RELAXED, __HIP_MEMORY_SCOPE_AGENT);
    }
    e = expf(Sv[n]-M);
  }
  __shared__ float red[256];
  __shared__ int lastflag;
  __shared__ unsigned lst[4096];
  __shared__ unsigned hh[128];
  __shared__ unsigned sPfx, sKp, sEq;
  red[tid]=e; __syncthreads();
  for (int st=128;st>0;st>>=1){ if (tid<st) red[tid]+=red[tid+st]; __syncthreads(); }
  if (tid==0) atomicAdd((float*)&SC[1], red[0]);
  __threadfence();
  __syncthreads();
  if (tid==0){
    unsigned d = atomicAdd(&SC[5], 1u);
    lastflag = (d == gridDim.x-1) ? 1 : 0;
  }
  __syncthreads();
  if (!lastflag) return;
  __threadfence();

  // ---- loss ----
  float v = 0.f;
  if (tid<L) v = Sv[labels[tid]];
  red[tid]=v; __syncthreads();
  for (int st=128;st>0;st>>=1){ if (tid<st) red[tid]+=red[tid+st]; __syncthreads(); }
  if (tid==0){
    float se = __hip_atomic_load((float*)&SC[1], __ATOMIC_RELAXED, __HIP_MEMORY_SCOPE_AGENT);
    out[0] = (float)L*(M + logf(se)) - red[0];
  }

  // ---- exact select among candidates (low 21 bits, 3x7-bit passes) ----
  unsigned cnt = __hip_atomic_load(&SC[2], __ATOMIC_RELAXED, __HIP_MEMORY_SCOPE_AGENT);
  if (cnt > EQCAP) cnt = EQCAP;
  if (tid==0){ sPfx=0u; sKp=SC[4]; sEq=0u; }
  __syncthreads();
  for (int p=0;p<3;++p){
    int shift = 14 - 7*p;
    if (tid<128) hh[tid]=0u;
    __syncthreads();
    unsigned pfx = sPfx;
    for (unsigned i=tid;i<cnt;i+=256u){
      unsigned idx = __hip_atomic_load(&EQL[i], __ATOMIC_RELAXED, __HIP_MEMORY_SCOPE_AGENT);
      unsigned key = UK[idx] & 0x1FFFFFu;
      if ((key>>(shift+7)) == pfx) atomicAdd(&hh[(key>>shift)&127u],1u);
    }
    __syncthreads();
    if (tid==0){
      unsigned Kp=sKp, cum=0; int sel=0;
      for (int b=127;b>=0;--b){ if (cum+hh[b]>=Kp){sel=b;break;} cum+=hh[b]; }
      sPfx = (pfx<<7)|(unsigned)sel; sKp = Kp - cum;
    }
    __syncthreads();
  }
  unsigned Tlow = sPfx;
  unsigned q = sKp;

  // mark: key > Tlow -> in; key == Tlow -> collect for index-ranked ties
  for (unsigned i=tid;i<cnt;i+=256u){
    unsigned idx = __hip_atomic_load(&EQL[i], __ATOMIC_RELAXED, __HIP_MEMORY_SCOPE_AGENT);
    unsigned key = UK[idx] & 0x1FFFFFu;
    if (key > Tlow) out[1+idx] = 1.0f;
    else if (key == Tlow){
      unsigned j = atomicAdd(&sEq,1u);
      if (j < 4096u) lst[j] = idx;
    }
  }
  __syncthreads();
  unsigned ec = sEq; if (ec>4096u) ec=4096u;
  for (unsigned i=tid;i<ec;i+=256u){
    unsigned me=lst[i], rank=0;
    for (unsigned j=0;j<ec;++j) rank += (lst[j]<me)?1u:0u;
    if (rank<q) out[1+me]=1.0f;   // stable tie-break: lowest index wins
  }
}

extern "C" void kernel_launch(void* const* d_in, const int* in_sizes, int n_in,
                              void* d_out, int out_size, void* d_ws, size_t ws_size,
                              hipStream_t stream)
{
  const float* emb  = (const float*)d_in[0];
  const float* dtab = (const float*)d_in[1];
  const float* W    = (const float*)d_in[2];
  const int* dist   = (const int*)d_in[3];
  const int* labels = (const int*)d_in[4];
  const int* srcp   = (const int*)d_in[5];
  float* out = (float*)d_out;
  int N = in_sizes[3];
  int L = in_sizes[4];

  float* ws = (float*)d_ws;
  float* UT = ws;                       // 36*1024 = 36864
  float* RE = UT + 36864;               // 256
  float* Bm = RE + 256;                 // 768
  float* Cc = Bm + 768;                 // 3
  float* RC = Cc + 3;                   // 3
  float* QN = RC + 3;                   // 1
  unsigned* SC = (unsigned*)(QN + 1);   // 8 scalars
  unsigned* H0 = SC + 8;                // 2048
  float* Sv = (float*)(H0 + 2048);      // N
  unsigned* UK = (unsigned*)(Sv + N);   // N
  unsigned* EQL = UK + N;               // 32768

  int grid  = (N + 255)/256;
  int grid2 = (N + 63)/64;
  k1_setup<<<257,256,0,stream>>>(emb, dtab, W, srcp, UT, RE, Bm, Cc, RC, QN, SC, H0);
  k2_main<<<grid2,256,0,stream>>>(emb, dist, UT, RE, Bm, Cc, RC, QN, Sv, UK, SC, H0, N);
  ksel0<<<1,256,0,stream>>>(SC, H0);
  k6_final<<<grid,256,0,stream>>>(dist, srcp, labels, Sv, UK, SC, EQL, out, N, L);
}